// Round 6
// baseline (262.219 us; speedup 1.0000x reference)
//
#include <hip/hip_runtime.h>
#include <hip/hip_bf16.h>

#define NB 16
#define VV 5000
#define NFD 352
#define KD 120
#define NCH 5
#define SLABSZ (352 * 120)

typedef __attribute__((ext_vector_type(8))) short short8;
typedef __attribute__((ext_vector_type(4))) float float4v;

__device__ __forceinline__ unsigned short bfb(float a) {
    return __builtin_bit_cast(unsigned short, __float2bfloat16(a));
}

// split fp32 -> bf16 hi + bf16 lo(residual), pack 8 of each into int4
__device__ __forceinline__ void pack8(const float* f, int4& hi, int4& lo) {
    unsigned short h[8], l[8];
    #pragma unroll
    for (int j = 0; j < 8; ++j) {
        const float a = f[j];
        const __hip_bfloat16 hb = __float2bfloat16(a);
        h[j] = __builtin_bit_cast(unsigned short, hb);
        l[j] = bfb(a - __bfloat162float(hb));
    }
    hi.x = h[0] | (h[1] << 16); hi.y = h[2] | (h[3] << 16);
    hi.z = h[4] | (h[5] << 16); hi.w = h[6] | (h[7] << 16);
    lo.x = l[0] | (l[1] << 16); lo.y = l[2] | (l[3] << 16);
    lo.z = l[4] | (l[5] << 16); lo.w = l[6] | (l[7] << 16);
}

// ---------------------------------------------------------------------------
// proj v2: F_hat[b,f,k] = sum_v feat[b,v,f]*evecs[b,v,k]
// Tile 128x128, BK=64, 4 waves as 2x2 (wave tile 64x64), mfma 16x16x32 bf16
// split hi/lo (3 products). LDS holds bf16 [m][64k] planes (A_hi,A_lo,B_hi,
// B_lo @ 16KB each), chunk-XOR swizzled: element (m,k) at byte
//   m*128 + (((k>>3) ^ (m&7))*16) + (k&7)*2   (+plane offset)
// Staging: lane owns (m, k-octet): 8 k-strided coalesced global dwords ->
// cvt once -> 2x ds_write_b128. Fragment (16 m x 8 k) = ONE ds_read_b128
// (lane l: m=l&15 within frag, k = 8*(l>>4)+j — same mapping as the verified
// round-3 kernel, only the LDS encoding changed).
// grid.x = mt(3) + 3*ch(5); grid.y = wh; grid.z = b.  480 blocks, 2/CU.
// ---------------------------------------------------------------------------
__global__ __launch_bounds__(256, 2) void proj_mfma(
    const float* __restrict__ fx, const float* __restrict__ fy,
    const float* __restrict__ ex, const float* __restrict__ ey,
    float* __restrict__ partials)
{
    const int t  = threadIdx.x;
    const int mt = blockIdx.x % 3;
    const int ch = blockIdx.x / 3;
    const int wh = blockIdx.y;
    const int b  = blockIdx.z;

    const float* Ab = (wh ? fy : fx) + (size_t)b * VV * NFD;
    const float* Bb = (wh ? ey : ex) + (size_t)b * VV * KD;
    const int m0 = mt * 128;

    __shared__ int4 smem4[4096];                 // 64 KB
    unsigned char* smem = (unsigned char*)smem4;

    // ---- staging precompute: 4 A units + 4 B units per lane ----
    int aoff[4], awb[4], ao[4];
    #pragma unroll
    for (int i = 0; i < 4; ++i) {
        const int q = i * 256 + t;
        const int m = q & 127;
        const int o = q >> 7;                    // k-octet 0..7
        const int col = min(m0 + m, NFD - 1);    // clamp: dup rows never stored
        aoff[i] = col + o * 8 * NFD;
        awb[i]  = m * 128 + ((o ^ (m & 7)) * 16);
        ao[i]   = o;
    }
    int boff[4], bwb[4], bo[4];
    #pragma unroll
    for (int i = 0; i < 4; ++i) {
        const int q = i * 256 + t;
        const int n = q & 127;
        const int o = q >> 7;
        const int col = min(n, KD - 1);          // clamp: dup cols never reduced
        boff[i] = col + o * 8 * KD;
        bwb[i]  = 32768 + n * 128 + ((o ^ (n & 7)) * 16);
        bo[i]   = o;
    }

    // ---- wave geometry ----
    const int lane = t & 63;
    const int wid  = t >> 6;
    const int wm = wid >> 1, wn = wid & 1;
    const int r16 = lane & 15;
    const int g   = lane >> 4;

    int abase[4], bbase[4];
    #pragma unroll
    for (int mf = 0; mf < 4; ++mf) {
        const int m = wm * 64 + mf * 16 + r16;
        abase[mf] = m * 128 + ((g ^ (m & 7)) * 16);
    }
    #pragma unroll
    for (int nf = 0; nf < 4; ++nf) {
        const int n = wn * 64 + nf * 16 + r16;
        bbase[nf] = 32768 + n * 128 + ((g ^ (n & 7)) * 16);
    }

    float4v acc[4][4];
    #pragma unroll
    for (int mf = 0; mf < 4; ++mf)
        #pragma unroll
        for (int nf = 0; nf < 4; ++nf)
            acc[mf][nf] = float4v{0.f, 0.f, 0.f, 0.f};

    const int step0 = ch * 16;
    const int nst   = (ch < 4) ? 16 : 15;        // 79 steps of 64 cover V=5000

    float fa[4][8], fb[4][8];

    // ---- load helper (macro-free, fully unrolled) ----
    auto do_loads = [&](int v0) {
        const int va = v0 * NFD;
        const int vb = v0 * KD;
        if (v0 + 64 <= VV) {
            #pragma unroll
            for (int i = 0; i < 4; ++i)
                #pragma unroll
                for (int j = 0; j < 8; ++j)
                    fa[i][j] = Ab[aoff[i] + va + j * NFD];
            #pragma unroll
            for (int i = 0; i < 4; ++i)
                #pragma unroll
                for (int j = 0; j < 8; ++j)
                    fb[i][j] = Bb[boff[i] + vb + j * KD];
        } else {
            #pragma unroll
            for (int i = 0; i < 4; ++i)
                #pragma unroll
                for (int j = 0; j < 8; ++j) {
                    const int v = v0 + ao[i] * 8 + j;
                    fa[i][j] = (v < VV) ? Ab[aoff[i] + va + j * NFD] : 0.f;
                }
            #pragma unroll
            for (int i = 0; i < 4; ++i)
                #pragma unroll
                for (int j = 0; j < 8; ++j) {
                    const int v = v0 + bo[i] * 8 + j;
                    fb[i][j] = (v < VV) ? Bb[boff[i] + vb + j * KD] : 0.f;
                }
        }
    };
    auto do_writes = [&]() {
        #pragma unroll
        for (int i = 0; i < 4; ++i) {
            int4 hi, lo;
            pack8(fa[i], hi, lo);
            *(int4*)(smem + awb[i])         = hi;
            *(int4*)(smem + awb[i] + 16384) = lo;
        }
        #pragma unroll
        for (int i = 0; i < 4; ++i) {
            int4 hi, lo;
            pack8(fb[i], hi, lo);
            *(int4*)(smem + bwb[i])         = hi;
            *(int4*)(smem + bwb[i] + 16384) = lo;
        }
    };

    // prologue: stage step 0
    do_loads(step0 * 64);
    do_writes();
    __syncthreads();

    for (int st = 0; st < nst; ++st) {
        const bool more = (st + 1 < nst);
        if (more) do_loads((step0 + st + 1) * 64);   // prefetch next tile

        #pragma unroll
        for (int ks = 0; ks < 2; ++ks) {
            short8 ah[4], al[4], bh[4], bl[4];
            #pragma unroll
            for (int mf = 0; mf < 4; ++mf) {
                const int ad = abase[mf] ^ (ks * 64);
                ah[mf] = *(const short8*)(smem + ad);
                al[mf] = *(const short8*)(smem + ad + 16384);
            }
            #pragma unroll
            for (int nf = 0; nf < 4; ++nf) {
                const int bd = bbase[nf] ^ (ks * 64);
                bh[nf] = *(const short8*)(smem + bd);
                bl[nf] = *(const short8*)(smem + bd + 16384);
            }
            #pragma unroll
            for (int mf = 0; mf < 4; ++mf)
                #pragma unroll
                for (int nf = 0; nf < 4; ++nf) {
                    acc[mf][nf] = __builtin_amdgcn_mfma_f32_16x16x32_bf16(ah[mf], bh[nf], acc[mf][nf], 0, 0, 0);
                    acc[mf][nf] = __builtin_amdgcn_mfma_f32_16x16x32_bf16(ah[mf], bl[nf], acc[mf][nf], 0, 0, 0);
                    acc[mf][nf] = __builtin_amdgcn_mfma_f32_16x16x32_bf16(al[mf], bh[nf], acc[mf][nf], 0, 0, 0);
                }
        }
        __syncthreads();          // all frag reads done
        if (more) {
            do_writes();          // publish next tile
            __syncthreads();
        }
    }

    // ---- store partial C tile: slab[m*120 + n] ----
    float* slab = partials + (size_t)((ch * 2 + wh) * NB + b) * SLABSZ;
    #pragma unroll
    for (int mf = 0; mf < 4; ++mf) {
        const int mrow = mt * 128 + wm * 64 + mf * 16 + g * 4;
        #pragma unroll
        for (int nf = 0; nf < 4; ++nf) {
            const int n = wn * 64 + nf * 16 + r16;
            if (n < KD) {
                #pragma unroll
                for (int r = 0; r < 4; ++r) {
                    const int m = mrow + r;
                    if (m < NFD) slab[(size_t)m * KD + n] = acc[mf][nf][r];
                }
            }
        }
    }
}

// ---------------------------------------------------------------------------
// reduce: fhat/ghat[b][f][k] = sum_ch partials[slab(ch,wh,b)][f*120 + k]
// ---------------------------------------------------------------------------
__global__ __launch_bounds__(256) void reduce_k(
    const float* __restrict__ partials, float* __restrict__ fhat, float* __restrict__ ghat)
{
    const int id = blockIdx.x * 256 + threadIdx.x;
    if (id >= NFD * KD) return;
    const int wb = blockIdx.y;
    const int wh = wb >> 4;
    const int b  = wb & 15;

    const float* p = partials + (size_t)(wh * NB + b) * SLABSZ + id;
    const size_t chstride = (size_t)2 * NB * SLABSZ;

    float s = 0.f;
    #pragma unroll
    for (int c = 0; c < NCH; ++c) s += p[c * chstride];

    float* dst = (wh ? ghat : fhat) + (size_t)b * NFD * KD + id;
    *dst = s;
}

// ---------------------------------------------------------------------------
// Generic TN SGEMM 64x64 tile — used by gram (unchanged, passing).
// ---------------------------------------------------------------------------
__device__ __forceinline__ void gemm_tn_64x64(
    const float* __restrict__ A, const float* __restrict__ B, float* __restrict__ C,
    int V, int M, int N, int m0, int n0)
{
    __shared__ float As[16][64];
    __shared__ float Bs[16][64];

    const int tid = threadIdx.x;
    const int tx = tid & 15;
    const int ty = tid >> 4;
    const int sr = tid >> 4;
    const int sc = (tid & 15) << 2;

    float acc[4][4] = {{0.f,0.f,0.f,0.f},{0.f,0.f,0.f,0.f},
                       {0.f,0.f,0.f,0.f},{0.f,0.f,0.f,0.f}};

    for (int v0 = 0; v0 < V; v0 += 16) {
        const int v = v0 + sr;
        float4 av; av.x = av.y = av.z = av.w = 0.f;
        float4 bv; bv.x = bv.y = bv.z = bv.w = 0.f;
        if (v < V) {
            const float* Ar = A + (size_t)v * M;
            const int ca = m0 + sc;
            if (ca + 3 < M) {
                av = *(const float4*)(Ar + ca);
            } else {
                if (ca + 0 < M) av.x = Ar[ca + 0];
                if (ca + 1 < M) av.y = Ar[ca + 1];
                if (ca + 2 < M) av.z = Ar[ca + 2];
                if (ca + 3 < M) av.w = Ar[ca + 3];
            }
            const float* Br = B + (size_t)v * N;
            const int cb = n0 + sc;
            if (cb + 3 < N) {
                bv = *(const float4*)(Br + cb);
            } else {
                if (cb + 0 < N) bv.x = Br[cb + 0];
                if (cb + 1 < N) bv.y = Br[cb + 1];
                if (cb + 2 < N) bv.z = Br[cb + 2];
                if (cb + 3 < N) bv.w = Br[cb + 3];
            }
        }
        __syncthreads();
        *(float4*)&As[sr][sc] = av;
        *(float4*)&Bs[sr][sc] = bv;
        __syncthreads();

        #pragma unroll
        for (int kk = 0; kk < 16; ++kk) {
            const float4 a4 = *(const float4*)&As[kk][ty << 2];
            const float4 b4 = *(const float4*)&Bs[kk][tx << 2];
            const float a[4]  = {a4.x, a4.y, a4.z, a4.w};
            const float bb[4] = {b4.x, b4.y, b4.z, b4.w};
            #pragma unroll
            for (int i = 0; i < 4; ++i)
                #pragma unroll
                for (int j = 0; j < 4; ++j)
                    acc[i][j] = fmaf(a[i], bb[j], acc[i][j]);
        }
    }

    #pragma unroll
    for (int i = 0; i < 4; ++i) {
        const int m = m0 + (ty << 2) + i;
        if (m < M) {
            #pragma unroll
            for (int j = 0; j < 4; ++j) {
                const int n = n0 + (tx << 2) + j;
                if (n < N) C[(size_t)m * N + n] = acc[i][j];
            }
        }
    }
}

__global__ __launch_bounds__(256) void gram_kernel(
    const float* __restrict__ fhat, const float* __restrict__ ghat,
    float* __restrict__ ftf, float* __restrict__ gtg, float* __restrict__ ftg)
{
    const int b = blockIdx.z;
    const int which = blockIdx.y;
    const int m0 = (blockIdx.x & 1) * 64;
    const int n0 = (blockIdx.x >> 1) * 64;

    const float* F = fhat + (size_t)b * NFD * KD;
    const float* G = ghat + (size_t)b * NFD * KD;
    const float* A  = (which == 1) ? G : F;
    const float* Bp = (which == 0) ? F : G;
    float* C = ((which == 0) ? ftf : (which == 1) ? gtg : ftg) + (size_t)b * KD * KD;

    gemm_tn_64x64(A, Bp, C, NFD, KD, KD, m0, n0);
}

// ---------------------------------------------------------------------------
// solve v5: v4's verified 960-thread/30-named-scalar Gauss-Jordan, with
// pivot-row reads widened to b128. prow stored as 8 padded segments of 32
// floats (seg = cg*32, 16B-aligned) so each lane reads its 30-col slice as
// 7x float4 + 1x float2 (31 scalar reads -> 9 wide reads; v4 was
// LDS-issue-bound at 2600 cy/step). Update uses c -= (f*pinv)*prow_raw.
// ---------------------------------------------------------------------------
__device__ __forceinline__ float ldval(const float* __restrict__ A, const float* __restrict__ B,
                                       int pair, int row, int col) {
    if (col < KD) return A[row * KD + col];
    const int l = col - KD;
    return pair ? B[l * KD + row] : B[row * KD + l];
}

#define FOR30(OP) OP(0) OP(1) OP(2) OP(3) OP(4) OP(5) OP(6) OP(7) OP(8) OP(9) \
                  OP(10) OP(11) OP(12) OP(13) OP(14) OP(15) OP(16) OP(17) OP(18) OP(19) \
                  OP(20) OP(21) OP(22) OP(23) OP(24) OP(25) OP(26) OP(27) OP(28) OP(29)

__global__ __launch_bounds__(960, 1) void solve_kernel(
    const float* __restrict__ ftf, const float* __restrict__ gtg,
    const float* __restrict__ ftg, float* __restrict__ out)
{
    const int pair = blockIdx.x;
    const int b = blockIdx.y;
    const int tid = threadIdx.x;
    const int row   = tid >> 3;   // 0..119
    const int cg    = tid & 7;    // 0..7
    const int cbase = cg * 30;    // first owned logical column
    const int seg   = cg * 32;    // physical segment base in prow

    const float* Ag = ((pair == 0) ? ftf : gtg) + (size_t)b * KD * KD;
    const float* Bg = ftg + (size_t)b * KD * KD;

    __shared__ __align__(16) float prow[2][256];   // [8 segs][32]
    __shared__ float pcol[2][120];

    #define DECLC(I) float c##I = ldval(Ag, Bg, pair, row, cbase + (I));
    FOR30(DECLC)
    #undef DECLC

    // ---- publish pivot row 0 / col 0 into buffer 0 ----
    if (row == 0) {
        float4 w;
        w = float4{c0,c1,c2,c3};     *(float4*)&prow[0][seg + 0]  = w;
        w = float4{c4,c5,c6,c7};     *(float4*)&prow[0][seg + 4]  = w;
        w = float4{c8,c9,c10,c11};   *(float4*)&prow[0][seg + 8]  = w;
        w = float4{c12,c13,c14,c15}; *(float4*)&prow[0][seg + 12] = w;
        w = float4{c16,c17,c18,c19}; *(float4*)&prow[0][seg + 16] = w;
        w = float4{c20,c21,c22,c23}; *(float4*)&prow[0][seg + 20] = w;
        w = float4{c24,c25,c26,c27}; *(float4*)&prow[0][seg + 24] = w;
        *(float2*)&prow[0][seg + 28] = float2{c28, c29};
    }
    if (cg == 0) pcol[0][row] = c0;
    __syncthreads();

    int iseg = 0, ioff = 0;   // (iseg,ioff) = segment/offset of logical col j

    for (int j = 0; j < KD; ++j) {
        const int cur = j & 1;
        const int nxt = cur ^ 1;

        const float pv   = prow[cur][(iseg << 5) + ioff];
        const float pinv = 1.0f / pv;
        const float f    = pcol[cur][row];
        const float fp   = f * pinv;

        const float4 r0 = *(const float4*)&prow[cur][seg + 0];
        const float4 r1 = *(const float4*)&prow[cur][seg + 4];
        const float4 r2 = *(const float4*)&prow[cur][seg + 8];
        const float4 r3 = *(const float4*)&prow[cur][seg + 12];
        const float4 r4 = *(const float4*)&prow[cur][seg + 16];
        const float4 r5 = *(const float4*)&prow[cur][seg + 20];
        const float4 r6 = *(const float4*)&prow[cur][seg + 24];
        const float2 r7 = *(const float2*)&prow[cur][seg + 28];

        // rank-1 update: c -= (f*pinv) * prow_raw
        c0  = fmaf(-fp, r0.x, c0);  c1  = fmaf(-fp, r0.y, c1);
        c2  = fmaf(-fp, r0.z, c2);  c3  = fmaf(-fp, r0.w, c3);
        c4  = fmaf(-fp, r1.x, c4);  c5  = fmaf(-fp, r1.y, c5);
        c6  = fmaf(-fp, r1.z, c6);  c7  = fmaf(-fp, r1.w, c7);
        c8  = fmaf(-fp, r2.x, c8);  c9  = fmaf(-fp, r2.y, c9);
        c10 = fmaf(-fp, r2.z, c10); c11 = fmaf(-fp, r2.w, c11);
        c12 = fmaf(-fp, r3.x, c12); c13 = fmaf(-fp, r3.y, c13);
        c14 = fmaf(-fp, r3.z, c14); c15 = fmaf(-fp, r3.w, c15);
        c16 = fmaf(-fp, r4.x, c16); c17 = fmaf(-fp, r4.y, c17);
        c18 = fmaf(-fp, r4.z, c18); c19 = fmaf(-fp, r4.w, c19);
        c20 = fmaf(-fp, r5.x, c20); c21 = fmaf(-fp, r5.y, c21);
        c22 = fmaf(-fp, r5.z, c22); c23 = fmaf(-fp, r5.w, c23);
        c24 = fmaf(-fp, r6.x, c24); c25 = fmaf(-fp, r6.y, c25);
        c26 = fmaf(-fp, r6.z, c26); c27 = fmaf(-fp, r6.w, c27);
        c28 = fmaf(-fp, r7.x, c28); c29 = fmaf(-fp, r7.y, c29);

        // pivot row becomes the scaled pivot row
        if (row == j) {
            c0  = r0.x * pinv; c1  = r0.y * pinv; c2  = r0.z * pinv; c3  = r0.w * pinv;
            c4  = r1.x * pinv; c5  = r1.y * pinv; c6  = r1.z * pinv; c7  = r1.w * pinv;
            c8  = r2.x * pinv; c9  = r2.y * pinv; c10 = r2.z * pinv; c11 = r2.w * pinv;
            c12 = r3.x * pinv; c13 = r3.y * pinv; c14 = r3.z * pinv; c15 = r3.w * pinv;
            c16 = r4.x * pinv; c17 = r4.y * pinv; c18 = r4.z * pinv; c19 = r4.w * pinv;
            c20 = r5.x * pinv; c21 = r5.y * pinv; c22 = r5.z * pinv; c23 = r5.w * pinv;
            c24 = r6.x * pinv; c25 = r6.y * pinv; c26 = r6.z * pinv; c27 = r6.w * pinv;
            c28 = r7.x * pinv; c29 = r7.y * pinv;
        }

        // publish NEXT pivot row (j+1)
        const int j2 = j + 1;
        if (row == j2) {
            float4 w;
            w = float4{c0,c1,c2,c3};     *(float4*)&prow[nxt][seg + 0]  = w;
            w = float4{c4,c5,c6,c7};     *(float4*)&prow[nxt][seg + 4]  = w;
            w = float4{c8,c9,c10,c11};   *(float4*)&prow[nxt][seg + 8]  = w;
            w = float4{c12,c13,c14,c15}; *(float4*)&prow[nxt][seg + 12] = w;
            w = float4{c16,c17,c18,c19}; *(float4*)&prow[nxt][seg + 16] = w;
            w = float4{c20,c21,c22,c23}; *(float4*)&prow[nxt][seg + 20] = w;
            w = float4{c24,c25,c26,c27}; *(float4*)&prow[nxt][seg + 24] = w;
            *(float2*)&prow[nxt][seg + 28] = float2{c28, c29};
        }

        // advance (iseg,ioff) to j+1, then publish NEXT pivot column
        ioff++; if (ioff == 30) { ioff = 0; iseg++; }
        if (j2 < KD && cg == iseg) {
            #define PCASE(I) case I: pcol[nxt][row] = c##I; break;
            switch (ioff) { FOR30(PCASE) default: break; }
            #undef PCASE
        }
        __syncthreads();
    }

    // ---- write out X^T: out[pair][b][l][k] = X[k][l]; X = cols 120..239 ----
    float* op = out + (size_t)pair * NB * KD * KD + (size_t)b * KD * KD;
    if (cg >= 4) {
        #define OUTW(I) { const int l = cbase + (I) - KD; op[l * KD + row] = c##I; }
        FOR30(OUTW)
        #undef OUTW
    }
}

// ---------------------------------------------------------------------------
extern "C" void kernel_launch(void* const* d_in, const int* in_sizes, int n_in,
                              void* d_out, int out_size, void* d_ws, size_t ws_size,
                              hipStream_t stream)
{
    const float* feat_x  = (const float*)d_in[0];
    const float* feat_y  = (const float*)d_in[1];
    const float* evecs_x = (const float*)d_in[2];
    const float* evecs_y = (const float*)d_in[3];
    float* out = (float*)d_out;

    // ws layout (floats):
    //   partials: NCH*2*NB slabs of 352*120 = 6,758,400   (27.0 MB)
    //   fhat/ghat: 675,840 each                           (+5.4 MB, total 32.4 MB)
    //   ftf/gtg/ftg alias the partials region (dead after reduce_k)
    float* ws       = (float*)d_ws;
    float* partials = ws;
    float* fhat     = partials + (size_t)NCH * 2 * NB * SLABSZ;
    float* ghat     = fhat + (size_t)NB * NFD * KD;
    float* ftf      = ws;                                 // aliases partials
    float* gtg      = ftf + (size_t)NB * KD * KD;
    float* ftg      = gtg + (size_t)NB * KD * KD;

    proj_mfma <<<dim3(15, 2, NB), 256, 0, stream>>>(feat_x, feat_y, evecs_x, evecs_y, partials);
    reduce_k  <<<dim3(165, 32), 256, 0, stream>>>(partials, fhat, ghat);
    gram_kernel<<<dim3(4, 3, NB), 256, 0, stream>>>(fhat, ghat, ftf, gtg, ftg);
    solve_kernel<<<dim3(2, NB), 960, 0, stream>>>(ftf, gtg, ftg, out);
}

// Round 7
// 211.036 us; speedup vs baseline: 1.2425x; 1.2425x over previous
//
#include <hip/hip_runtime.h>
#include <hip/hip_bf16.h>

#define NB 16
#define VV 5000
#define NFD 352
#define KD 120
#define NCH 5
#define SLABSZ (352 * 120)

typedef __attribute__((ext_vector_type(8))) short short8;
typedef __attribute__((ext_vector_type(4))) float float4v;

__device__ __forceinline__ unsigned short bfb(float a) {
    return __builtin_bit_cast(unsigned short, __float2bfloat16(a));
}

// split fp32 -> bf16 hi + bf16 lo(residual), pack 8 of each into int4
__device__ __forceinline__ void pack8(const float* f, int4& hi, int4& lo) {
    unsigned short h[8], l[8];
    #pragma unroll
    for (int j = 0; j < 8; ++j) {
        const float a = f[j];
        const __hip_bfloat16 hb = __float2bfloat16(a);
        h[j] = __builtin_bit_cast(unsigned short, hb);
        l[j] = bfb(a - __bfloat162float(hb));
    }
    hi.x = h[0] | (h[1] << 16); hi.y = h[2] | (h[3] << 16);
    hi.z = h[4] | (h[5] << 16); hi.w = h[6] | (h[7] << 16);
    lo.x = l[0] | (l[1] << 16); lo.y = l[2] | (l[3] << 16);
    lo.z = l[4] | (l[5] << 16); lo.w = l[6] | (l[7] << 16);
}

// ---------------------------------------------------------------------------
// proj v2 (unchanged from round 6, passing): F_hat[b,f,k] = sum_v feat*evecs
// ---------------------------------------------------------------------------
__global__ __launch_bounds__(256, 2) void proj_mfma(
    const float* __restrict__ fx, const float* __restrict__ fy,
    const float* __restrict__ ex, const float* __restrict__ ey,
    float* __restrict__ partials)
{
    const int t  = threadIdx.x;
    const int mt = blockIdx.x % 3;
    const int ch = blockIdx.x / 3;
    const int wh = blockIdx.y;
    const int b  = blockIdx.z;

    const float* Ab = (wh ? fy : fx) + (size_t)b * VV * NFD;
    const float* Bb = (wh ? ey : ex) + (size_t)b * VV * KD;
    const int m0 = mt * 128;

    __shared__ int4 smem4[4096];                 // 64 KB
    unsigned char* smem = (unsigned char*)smem4;

    int aoff[4], awb[4], ao[4];
    #pragma unroll
    for (int i = 0; i < 4; ++i) {
        const int q = i * 256 + t;
        const int m = q & 127;
        const int o = q >> 7;
        const int col = min(m0 + m, NFD - 1);
        aoff[i] = col + o * 8 * NFD;
        awb[i]  = m * 128 + ((o ^ (m & 7)) * 16);
        ao[i]   = o;
    }
    int boff[4], bwb[4], bo[4];
    #pragma unroll
    for (int i = 0; i < 4; ++i) {
        const int q = i * 256 + t;
        const int n = q & 127;
        const int o = q >> 7;
        const int col = min(n, KD - 1);
        boff[i] = col + o * 8 * KD;
        bwb[i]  = 32768 + n * 128 + ((o ^ (n & 7)) * 16);
        bo[i]   = o;
    }

    const int lane = t & 63;
    const int wid  = t >> 6;
    const int wm = wid >> 1, wn = wid & 1;
    const int r16 = lane & 15;
    const int g   = lane >> 4;

    int abase[4], bbase[4];
    #pragma unroll
    for (int mf = 0; mf < 4; ++mf) {
        const int m = wm * 64 + mf * 16 + r16;
        abase[mf] = m * 128 + ((g ^ (m & 7)) * 16);
    }
    #pragma unroll
    for (int nf = 0; nf < 4; ++nf) {
        const int n = wn * 64 + nf * 16 + r16;
        bbase[nf] = 32768 + n * 128 + ((g ^ (n & 7)) * 16);
    }

    float4v acc[4][4];
    #pragma unroll
    for (int mf = 0; mf < 4; ++mf)
        #pragma unroll
        for (int nf = 0; nf < 4; ++nf)
            acc[mf][nf] = float4v{0.f, 0.f, 0.f, 0.f};

    const int step0 = ch * 16;
    const int nst   = (ch < 4) ? 16 : 15;

    float fa[4][8], fb[4][8];

    auto do_loads = [&](int v0) {
        const int va = v0 * NFD;
        const int vb = v0 * KD;
        if (v0 + 64 <= VV) {
            #pragma unroll
            for (int i = 0; i < 4; ++i)
                #pragma unroll
                for (int j = 0; j < 8; ++j)
                    fa[i][j] = Ab[aoff[i] + va + j * NFD];
            #pragma unroll
            for (int i = 0; i < 4; ++i)
                #pragma unroll
                for (int j = 0; j < 8; ++j)
                    fb[i][j] = Bb[boff[i] + vb + j * KD];
        } else {
            #pragma unroll
            for (int i = 0; i < 4; ++i)
                #pragma unroll
                for (int j = 0; j < 8; ++j) {
                    const int v = v0 + ao[i] * 8 + j;
                    fa[i][j] = (v < VV) ? Ab[aoff[i] + va + j * NFD] : 0.f;
                }
            #pragma unroll
            for (int i = 0; i < 4; ++i)
                #pragma unroll
                for (int j = 0; j < 8; ++j) {
                    const int v = v0 + bo[i] * 8 + j;
                    fb[i][j] = (v < VV) ? Bb[boff[i] + vb + j * KD] : 0.f;
                }
        }
    };
    auto do_writes = [&]() {
        #pragma unroll
        for (int i = 0; i < 4; ++i) {
            int4 hi, lo;
            pack8(fa[i], hi, lo);
            *(int4*)(smem + awb[i])         = hi;
            *(int4*)(smem + awb[i] + 16384) = lo;
        }
        #pragma unroll
        for (int i = 0; i < 4; ++i) {
            int4 hi, lo;
            pack8(fb[i], hi, lo);
            *(int4*)(smem + bwb[i])         = hi;
            *(int4*)(smem + bwb[i] + 16384) = lo;
        }
    };

    do_loads(step0 * 64);
    do_writes();
    __syncthreads();

    for (int st = 0; st < nst; ++st) {
        const bool more = (st + 1 < nst);
        if (more) do_loads((step0 + st + 1) * 64);

        #pragma unroll
        for (int ks = 0; ks < 2; ++ks) {
            short8 ah[4], al[4], bh[4], bl[4];
            #pragma unroll
            for (int mf = 0; mf < 4; ++mf) {
                const int ad = abase[mf] ^ (ks * 64);
                ah[mf] = *(const short8*)(smem + ad);
                al[mf] = *(const short8*)(smem + ad + 16384);
            }
            #pragma unroll
            for (int nf = 0; nf < 4; ++nf) {
                const int bd = bbase[nf] ^ (ks * 64);
                bh[nf] = *(const short8*)(smem + bd);
                bl[nf] = *(const short8*)(smem + bd + 16384);
            }
            #pragma unroll
            for (int mf = 0; mf < 4; ++mf)
                #pragma unroll
                for (int nf = 0; nf < 4; ++nf) {
                    acc[mf][nf] = __builtin_amdgcn_mfma_f32_16x16x32_bf16(ah[mf], bh[nf], acc[mf][nf], 0, 0, 0);
                    acc[mf][nf] = __builtin_amdgcn_mfma_f32_16x16x32_bf16(ah[mf], bl[nf], acc[mf][nf], 0, 0, 0);
                    acc[mf][nf] = __builtin_amdgcn_mfma_f32_16x16x32_bf16(al[mf], bh[nf], acc[mf][nf], 0, 0, 0);
                }
        }
        __syncthreads();
        if (more) {
            do_writes();
            __syncthreads();
        }
    }

    float* slab = partials + (size_t)((ch * 2 + wh) * NB + b) * SLABSZ;
    #pragma unroll
    for (int mf = 0; mf < 4; ++mf) {
        const int mrow = mt * 128 + wm * 64 + mf * 16 + g * 4;
        #pragma unroll
        for (int nf = 0; nf < 4; ++nf) {
            const int n = wn * 64 + nf * 16 + r16;
            if (n < KD) {
                #pragma unroll
                for (int r = 0; r < 4; ++r) {
                    const int m = mrow + r;
                    if (m < NFD) slab[(size_t)m * KD + n] = acc[mf][nf][r];
                }
            }
        }
    }
}

// ---------------------------------------------------------------------------
// reduce (unchanged)
// ---------------------------------------------------------------------------
__global__ __launch_bounds__(256) void reduce_k(
    const float* __restrict__ partials, float* __restrict__ fhat, float* __restrict__ ghat)
{
    const int id = blockIdx.x * 256 + threadIdx.x;
    if (id >= NFD * KD) return;
    const int wb = blockIdx.y;
    const int wh = wb >> 4;
    const int b  = wb & 15;

    const float* p = partials + (size_t)(wh * NB + b) * SLABSZ + id;
    const size_t chstride = (size_t)2 * NB * SLABSZ;

    float s = 0.f;
    #pragma unroll
    for (int c = 0; c < NCH; ++c) s += p[c * chstride];

    float* dst = (wh ? ghat : fhat) + (size_t)b * NFD * KD + id;
    *dst = s;
}

// ---------------------------------------------------------------------------
// Generic TN SGEMM 64x64 tile — used by gram (unchanged, passing).
// ---------------------------------------------------------------------------
__device__ __forceinline__ void gemm_tn_64x64(
    const float* __restrict__ A, const float* __restrict__ B, float* __restrict__ C,
    int V, int M, int N, int m0, int n0)
{
    __shared__ float As[16][64];
    __shared__ float Bs[16][64];

    const int tid = threadIdx.x;
    const int tx = tid & 15;
    const int ty = tid >> 4;
    const int sr = tid >> 4;
    const int sc = (tid & 15) << 2;

    float acc[4][4] = {{0.f,0.f,0.f,0.f},{0.f,0.f,0.f,0.f},
                       {0.f,0.f,0.f,0.f},{0.f,0.f,0.f,0.f}};

    for (int v0 = 0; v0 < V; v0 += 16) {
        const int v = v0 + sr;
        float4 av; av.x = av.y = av.z = av.w = 0.f;
        float4 bv; bv.x = bv.y = bv.z = bv.w = 0.f;
        if (v < V) {
            const float* Ar = A + (size_t)v * M;
            const int ca = m0 + sc;
            if (ca + 3 < M) {
                av = *(const float4*)(Ar + ca);
            } else {
                if (ca + 0 < M) av.x = Ar[ca + 0];
                if (ca + 1 < M) av.y = Ar[ca + 1];
                if (ca + 2 < M) av.z = Ar[ca + 2];
                if (ca + 3 < M) av.w = Ar[ca + 3];
            }
            const float* Br = B + (size_t)v * N;
            const int cb = n0 + sc;
            if (cb + 3 < N) {
                bv = *(const float4*)(Br + cb);
            } else {
                if (cb + 0 < N) bv.x = Br[cb + 0];
                if (cb + 1 < N) bv.y = Br[cb + 1];
                if (cb + 2 < N) bv.z = Br[cb + 2];
                if (cb + 3 < N) bv.w = Br[cb + 3];
            }
        }
        __syncthreads();
        *(float4*)&As[sr][sc] = av;
        *(float4*)&Bs[sr][sc] = bv;
        __syncthreads();

        #pragma unroll
        for (int kk = 0; kk < 16; ++kk) {
            const float4 a4 = *(const float4*)&As[kk][ty << 2];
            const float4 b4 = *(const float4*)&Bs[kk][tx << 2];
            const float a[4]  = {a4.x, a4.y, a4.z, a4.w};
            const float bb[4] = {b4.x, b4.y, b4.z, b4.w};
            #pragma unroll
            for (int i = 0; i < 4; ++i)
                #pragma unroll
                for (int j = 0; j < 4; ++j)
                    acc[i][j] = fmaf(a[i], bb[j], acc[i][j]);
        }
    }

    #pragma unroll
    for (int i = 0; i < 4; ++i) {
        const int m = m0 + (ty << 2) + i;
        if (m < M) {
            #pragma unroll
            for (int j = 0; j < 4; ++j) {
                const int n = n0 + (tx << 2) + j;
                if (n < N) C[(size_t)m * N + n] = acc[i][j];
            }
        }
    }
}

__global__ __launch_bounds__(256) void gram_kernel(
    const float* __restrict__ fhat, const float* __restrict__ ghat,
    float* __restrict__ ftf, float* __restrict__ gtg, float* __restrict__ ftg)
{
    const int b = blockIdx.z;
    const int which = blockIdx.y;
    const int m0 = (blockIdx.x & 1) * 64;
    const int n0 = (blockIdx.x >> 1) * 64;

    const float* F = fhat + (size_t)b * NFD * KD;
    const float* G = ghat + (size_t)b * NFD * KD;
    const float* A  = (which == 1) ? G : F;
    const float* Bp = (which == 0) ? F : G;
    float* C = ((which == 0) ? ftf : (which == 1) ? gtg : ftg) + (size_t)b * KD * KD;

    gemm_tn_64x64(A, Bp, C, NFD, KD, KD, m0, n0);
}

// ---------------------------------------------------------------------------
// solve v6: Gauss-Jordan on [A|B] 120x240.
// 480 threads: rg = tid>>4 (0..29) owns rows rg*4..+3; cg = tid&15 (0..15)
// owns cols cg*15..+14. 60 NAMED scalars (rows w/x/y/z x 15 cols) — no
// arrays (v1/v2 spilled). Per step each thread: 4x b128 prow reads (padded
// 20-float segments -> banks 20*cg%32, only free 2-way cg/cg+8 aliasing;
// v5's 32-float segments all hit bank 0 = 8-way = 5.4M conflicts) + 1x b128
// pcol read, 4 muls + 60 FMA, publish next pivot row/col, 1 barrier.
// R=4 rows/thread cuts LDS traffic 3.2x vs v4 (each prow slice re-used for
// 4 rows): 9.1K floats/step vs 29.8K.
// pair 0: X = inv(FtF)*FtG, C1 = X^T; pair 1: X = inv(GtG)*FtG^T, C2 = X^T
// ---------------------------------------------------------------------------
__device__ __forceinline__ float ldval(const float* __restrict__ A, const float* __restrict__ B,
                                       int pair, int row, int col) {
    if (col < KD) return A[row * KD + col];
    const int l = col - KD;
    return pair ? B[l * KD + row] : B[row * KD + l];
}

#define FOR15(OP) OP(0) OP(1) OP(2) OP(3) OP(4) OP(5) OP(6) OP(7) OP(8) OP(9) \
                  OP(10) OP(11) OP(12) OP(13) OP(14)

__global__ __launch_bounds__(480, 1) void solve_kernel(
    const float* __restrict__ ftf, const float* __restrict__ gtg,
    const float* __restrict__ ftg, float* __restrict__ out)
{
    const int pair = blockIdx.x;
    const int b = blockIdx.y;
    const int tid = threadIdx.x;
    const int cg = tid & 15;     // col group: cols cg*15 .. +14
    const int rg = tid >> 4;     // row group: rows rg*4 .. +3
    const int cbase = cg * 15;
    const int r0 = rg * 4;
    const int seg = cg * 20;     // padded prow segment (20 floats = 80 B)

    const float* Ag = ((pair == 0) ? ftf : gtg) + (size_t)b * KD * KD;
    const float* Bg = ftg + (size_t)b * KD * KD;

    __shared__ __align__(16) float prow[2][320];   // 16 segs x 20
    __shared__ __align__(16) float pcol[2][120];

    // ---- 60 named scalars: rows w(r0) x(r0+1) y(r0+2) z(r0+3) ----
    #define DECL(I) float w##I = ldval(Ag, Bg, pair, r0 + 0, cbase + (I)); \
                    float x##I = ldval(Ag, Bg, pair, r0 + 1, cbase + (I)); \
                    float y##I = ldval(Ag, Bg, pair, r0 + 2, cbase + (I)); \
                    float z##I = ldval(Ag, Bg, pair, r0 + 3, cbase + (I));
    FOR15(DECL)
    #undef DECL

    // ---- publish pivot row 0 / pivot col 0 into buffer 0 ----
    if (rg == 0) {
        #define PUB0(I) prow[0][seg + (I)] = w##I;
        FOR15(PUB0)
        #undef PUB0
    }
    if (cg == 0) *(float4*)&pcol[0][r0] = float4{w0, x0, y0, z0};
    __syncthreads();

    int jseg = 0, joff = 0;   // position of current pivot col j

    for (int j = 0; j < KD; ++j) {
        const int cur = j & 1;
        const int nxt = cur ^ 1;

        const float pinv = 1.0f / prow[cur][jseg * 20 + joff];
        const float4 f4 = *(const float4*)&pcol[cur][r0];

        const float4 q0 = *(const float4*)&prow[cur][seg + 0];
        const float4 q1 = *(const float4*)&prow[cur][seg + 4];
        const float4 q2 = *(const float4*)&prow[cur][seg + 8];
        const float4 q3 = *(const float4*)&prow[cur][seg + 12];
        const float p0 = q0.x, p1 = q0.y, p2 = q0.z, p3 = q0.w;
        const float p4 = q1.x, p5 = q1.y, p6 = q1.z, p7 = q1.w;
        const float p8 = q2.x, p9 = q2.y, p10 = q2.z, p11 = q2.w;
        const float p12 = q3.x, p13 = q3.y, p14 = q3.z;

        const float fw = f4.x * pinv, fx = f4.y * pinv;
        const float fy = f4.z * pinv, fz = f4.w * pinv;

        #define UPD(I) w##I = fmaf(-fw, p##I, w##I); x##I = fmaf(-fx, p##I, x##I); \
                       y##I = fmaf(-fy, p##I, y##I); z##I = fmaf(-fz, p##I, z##I);
        FOR15(UPD)
        #undef UPD

        // pivot row becomes the scaled pivot row (UPD junked it; overwrite all 15)
        if (rg == (j >> 2)) {
            #define FW(I) w##I = p##I * pinv;
            #define FX(I) x##I = p##I * pinv;
            #define FY(I) y##I = p##I * pinv;
            #define FZ(I) z##I = p##I * pinv;
            switch (j & 3) {
                case 0: FOR15(FW) break;
                case 1: FOR15(FX) break;
                case 2: FOR15(FY) break;
                default: FOR15(FZ) break;
            }
            #undef FW
            #undef FX
            #undef FY
            #undef FZ
        }

        const int j2 = j + 1;

        // publish NEXT pivot row (j+1): owning rg's 16 threads, 15 entries each
        if (j2 < KD && rg == (j2 >> 2)) {
            #define PW(I) prow[nxt][seg + (I)] = w##I;
            #define PX(I) prow[nxt][seg + (I)] = x##I;
            #define PY(I) prow[nxt][seg + (I)] = y##I;
            #define PZ(I) prow[nxt][seg + (I)] = z##I;
            switch (j2 & 3) {
                case 0: FOR15(PW) break;
                case 1: FOR15(PX) break;
                case 2: FOR15(PY) break;
                default: FOR15(PZ) break;
            }
            #undef PW
            #undef PX
            #undef PY
            #undef PZ
        }

        // advance (jseg,joff) to j+1, then publish NEXT pivot column:
        // owning cg's 30 threads store float4{w,x,y,z}[joff] at rows r0..r0+3
        joff++; if (joff == 15) { joff = 0; jseg++; }
        if (j2 < KD && cg == jseg) {
            #define PC(I) case I: *(float4*)&pcol[nxt][r0] = float4{w##I, x##I, y##I, z##I}; break;
            switch (joff) {
                FOR15(PC)
                default: break;
            }
            #undef PC
        }
        __syncthreads();
    }

    // ---- write out X^T: out[pair][b][l][k] = X[k][l]; X = cols 120..239 (cg>=8) ----
    if (cg >= 8) {
        float* op = out + (size_t)pair * NB * KD * KD + (size_t)b * KD * KD;
        #define OUTW(I) { const int l = cbase + (I) - KD; \
                          *(float4*)&op[l * KD + r0] = float4{w##I, x##I, y##I, z##I}; }
        FOR15(OUTW)
        #undef OUTW
    }
}

// ---------------------------------------------------------------------------
extern "C" void kernel_launch(void* const* d_in, const int* in_sizes, int n_in,
                              void* d_out, int out_size, void* d_ws, size_t ws_size,
                              hipStream_t stream)
{
    const float* feat_x  = (const float*)d_in[0];
    const float* feat_y  = (const float*)d_in[1];
    const float* evecs_x = (const float*)d_in[2];
    const float* evecs_y = (const float*)d_in[3];
    float* out = (float*)d_out;

    float* ws       = (float*)d_ws;
    float* partials = ws;
    float* fhat     = partials + (size_t)NCH * 2 * NB * SLABSZ;
    float* ghat     = fhat + (size_t)NB * NFD * KD;
    float* ftf      = ws;                                 // aliases partials (dead after reduce)
    float* gtg      = ftf + (size_t)NB * KD * KD;
    float* ftg      = gtg + (size_t)NB * KD * KD;

    proj_mfma <<<dim3(15, 2, NB), 256, 0, stream>>>(feat_x, feat_y, evecs_x, evecs_y, partials);
    reduce_k  <<<dim3(165, 32), 256, 0, stream>>>(partials, fhat, ghat);
    gram_kernel<<<dim3(4, 3, NB), 256, 0, stream>>>(fhat, ghat, ftf, gtg, ftg);
    solve_kernel<<<dim3(2, NB), 480, 0, stream>>>(ftf, gtg, ftg, out);
}

// Round 8
// 208.801 us; speedup vs baseline: 1.2558x; 1.0107x over previous
//
#include <hip/hip_runtime.h>
#include <hip/hip_bf16.h>

#define NB 16
#define VV 5000
#define NFD 352
#define KD 120
#define NCH 5
#define SLABSZ (352 * 120)

typedef __attribute__((ext_vector_type(8))) short short8;
typedef __attribute__((ext_vector_type(4))) float float4v;

__device__ __forceinline__ unsigned short bfb(float a) {
    return __builtin_bit_cast(unsigned short, __float2bfloat16(a));
}

// split fp32 -> bf16 hi + bf16 lo(residual), pack 8 of each into int4
__device__ __forceinline__ void pack8(const float* f, int4& hi, int4& lo) {
    unsigned short h[8], l[8];
    #pragma unroll
    for (int j = 0; j < 8; ++j) {
        const float a = f[j];
        const __hip_bfloat16 hb = __float2bfloat16(a);
        h[j] = __builtin_bit_cast(unsigned short, hb);
        l[j] = bfb(a - __bfloat162float(hb));
    }
    hi.x = h[0] | (h[1] << 16); hi.y = h[2] | (h[3] << 16);
    hi.z = h[4] | (h[5] << 16); hi.w = h[6] | (h[7] << 16);
    lo.x = l[0] | (l[1] << 16); lo.y = l[2] | (l[3] << 16);
    lo.z = l[4] | (l[5] << 16); lo.w = l[6] | (l[7] << 16);
}

// ---------------------------------------------------------------------------
// proj v3: F_hat[b,f,k] = sum_v feat[b,v,f]*evecs[b,v,k]
// BK=32, double-buffered LDS ping-pong (2 x 32KB), 2-deep register prefetch
// (P/Q named sets), ONE barrier per step: loads(st+2) || compute(st) ||
// pack+write(st+1 -> other buf). v2 was phase-serialization bound (MfmaUtil
// 15%, HBM 23%): conversion+staging sat between barriers as MFMA-dead time.
// LDS per plane: (m,k-octet o) at m*64 + ((o ^ ((m>>1)&3))*16) — write b128
// (64 consecutive m, fixed o) and read b128 (16 consecutive m, fixed g) both
// bank-conflict-free. Planes: A_hi 0 | A_lo 8K | B_hi 16K | B_lo 24K; +32K/buf.
// XCD swizzle (480 = 8*60, bijective): 3 mt-tiles sharing a B panel (2.4MB,
// L2-fits) land on the same XCD.
// ---------------------------------------------------------------------------
__global__ __launch_bounds__(256, 2) void proj_mfma(
    const float* __restrict__ fx, const float* __restrict__ fy,
    const float* __restrict__ ex, const float* __restrict__ ey,
    float* __restrict__ partials)
{
    const int t = threadIdx.x;

    // ---- bijective XCD-chunk swizzle: 480 blocks = 8 XCDs x 60 ----
    int lin = blockIdx.x + 15 * (blockIdx.y + 2 * blockIdx.z);
    lin = (lin & 7) * 60 + (lin >> 3);
    const int xx   = lin % 15;
    const int rest = lin / 15;
    const int wh = rest & 1;
    const int b  = rest >> 1;
    const int mt = xx % 3;
    const int ch = xx / 3;

    const float* Ab = (wh ? fy : fx) + (size_t)b * VV * NFD;
    const float* Bb = (wh ? ey : ex) + (size_t)b * VV * KD;
    const int m0 = mt * 128;

    __shared__ int4 smem4[4096];                 // 64 KB = 2 x 32KB buffers
    unsigned char* smem = (unsigned char*)smem4;

    // ---- staging precompute: 2 A units + 2 B units (m, k-octet) ----
    int acol[2], awb[2], ao[2];
    #pragma unroll
    for (int i = 0; i < 2; ++i) {
        const int q = i * 256 + t;               // 0..511
        const int m = q & 127;
        const int o = q >> 7;                    // k-octet 0..3
        acol[i] = min(m0 + m, NFD - 1);          // clamp: dup cols never stored to C
        awb[i]  = m * 64 + ((o ^ ((m >> 1) & 3)) * 16);
        ao[i]   = o;
    }
    int bcol[2], bwb[2], bo[2];
    #pragma unroll
    for (int i = 0; i < 2; ++i) {
        const int q = i * 256 + t;
        const int n = q & 127;
        const int o = q >> 7;
        bcol[i] = min(n, KD - 1);
        bwb[i]  = n * 64 + ((o ^ ((n >> 1) & 3)) * 16);
        bo[i]   = o;
    }

    // ---- wave geometry: 4 waves as 2x2, wave tile 64x64 ----
    const int lane = t & 63;
    const int wid  = t >> 6;
    const int wm = wid >> 1, wn = wid & 1;
    const int r16 = lane & 15;
    const int g   = lane >> 4;

    int abase[4], bbase[4];
    #pragma unroll
    for (int mf = 0; mf < 4; ++mf) {
        const int m = wm * 64 + mf * 16 + r16;
        abase[mf] = m * 64 + ((g ^ ((m >> 1) & 3)) * 16);
    }
    #pragma unroll
    for (int nf = 0; nf < 4; ++nf) {
        const int n = wn * 64 + nf * 16 + r16;
        bbase[nf] = n * 64 + ((g ^ ((n >> 1) & 3)) * 16);
    }

    float4v acc[4][4];
    #pragma unroll
    for (int mf = 0; mf < 4; ++mf)
        #pragma unroll
        for (int nf = 0; nf < 4; ++nf)
            acc[mf][nf] = float4v{0.f, 0.f, 0.f, 0.f};

    const int step0 = ch * 32;                   // V-steps of 32
    const int nst   = (ch < 4) ? 32 : 30;        // 4*32+30 = 158 steps >= 5000/32

    float faP[2][8], fbP[2][8], faQ[2][8], fbQ[2][8];

    auto do_loads = [&](int st, float (&fa)[2][8], float (&fb)[2][8]) {
        const int v0 = (step0 + st) * 32;
        if (v0 + 32 <= VV) {
            #pragma unroll
            for (int i = 0; i < 2; ++i) {
                const float* pa = Ab + (size_t)(v0 + ao[i] * 8) * NFD + acol[i];
                #pragma unroll
                for (int j = 0; j < 8; ++j) fa[i][j] = pa[j * NFD];
            }
            #pragma unroll
            for (int i = 0; i < 2; ++i) {
                const float* pb = Bb + (size_t)(v0 + bo[i] * 8) * KD + bcol[i];
                #pragma unroll
                for (int j = 0; j < 8; ++j) fb[i][j] = pb[j * KD];
            }
        } else {
            #pragma unroll
            for (int i = 0; i < 2; ++i) {
                const float* pa = Ab + (size_t)(v0 + ao[i] * 8) * NFD + acol[i];
                #pragma unroll
                for (int j = 0; j < 8; ++j) {
                    const int v = v0 + ao[i] * 8 + j;
                    fa[i][j] = (v < VV) ? pa[j * NFD] : 0.f;
                }
            }
            #pragma unroll
            for (int i = 0; i < 2; ++i) {
                const float* pb = Bb + (size_t)(v0 + bo[i] * 8) * KD + bcol[i];
                #pragma unroll
                for (int j = 0; j < 8; ++j) {
                    const int v = v0 + bo[i] * 8 + j;
                    fb[i][j] = (v < VV) ? pb[j * KD] : 0.f;
                }
            }
        }
    };

    auto do_writes = [&](int bufb, float (&fa)[2][8], float (&fb)[2][8]) {
        #pragma unroll
        for (int i = 0; i < 2; ++i) {
            int4 hi, lo;
            pack8(fa[i], hi, lo);
            *(int4*)(smem + bufb + awb[i])        = hi;
            *(int4*)(smem + bufb + awb[i] + 8192) = lo;
        }
        #pragma unroll
        for (int i = 0; i < 2; ++i) {
            int4 hi, lo;
            pack8(fb[i], hi, lo);
            *(int4*)(smem + bufb + 16384 + bwb[i]) = hi;
            *(int4*)(smem + bufb + 24576 + bwb[i]) = lo;
        }
    };

    auto compute = [&](int bufb) {
        short8 ah[4], al[4], bh[4], bl[4];
        #pragma unroll
        for (int mf = 0; mf < 4; ++mf) {
            ah[mf] = *(const short8*)(smem + bufb + abase[mf]);
            al[mf] = *(const short8*)(smem + bufb + abase[mf] + 8192);
        }
        #pragma unroll
        for (int nf = 0; nf < 4; ++nf) {
            bh[nf] = *(const short8*)(smem + bufb + 16384 + bbase[nf]);
            bl[nf] = *(const short8*)(smem + bufb + 24576 + bbase[nf]);
        }
        #pragma unroll
        for (int mf = 0; mf < 4; ++mf)
            #pragma unroll
            for (int nf = 0; nf < 4; ++nf) {
                acc[mf][nf] = __builtin_amdgcn_mfma_f32_16x16x32_bf16(ah[mf], bh[nf], acc[mf][nf], 0, 0, 0);
                acc[mf][nf] = __builtin_amdgcn_mfma_f32_16x16x32_bf16(ah[mf], bl[nf], acc[mf][nf], 0, 0, 0);
                acc[mf][nf] = __builtin_amdgcn_mfma_f32_16x16x32_bf16(al[mf], bh[nf], acc[mf][nf], 0, 0, 0);
            }
    };

    // ---- prologue: prefetch steps 0,1; publish step 0 into buf0 ----
    do_loads(0, faP, fbP);
    do_loads(1, faQ, fbQ);
    do_writes(0, faP, fbP);
    __syncthreads();

    // ---- main loop: 2 steps per iteration, 1 barrier per step ----
    for (int i = 0; i < nst / 2; ++i) {
        const int st = 2 * i;
        // even step: compute buf0; stage st+1 into buf1; prefetch st+2
        if (st + 2 < nst) do_loads(st + 2, faP, fbP);
        compute(0);
        do_writes(32768, faQ, fbQ);          // st+1 (always < nst: nst even)
        __syncthreads();
        // odd step: compute buf1; stage st+2 into buf0; prefetch st+3
        if (st + 3 < nst) do_loads(st + 3, faQ, fbQ);
        compute(32768);
        if (st + 2 < nst) do_writes(0, faP, fbP);
        __syncthreads();
    }

    // ---- store partial C tile: slab[m*120 + n] ----
    float* slab = partials + (size_t)((ch * 2 + wh) * NB + b) * SLABSZ;
    #pragma unroll
    for (int mf = 0; mf < 4; ++mf) {
        const int mrow = mt * 128 + wm * 64 + mf * 16 + g * 4;
        #pragma unroll
        for (int nf = 0; nf < 4; ++nf) {
            const int n = wn * 64 + nf * 16 + r16;
            if (n < KD) {
                #pragma unroll
                for (int r = 0; r < 4; ++r) {
                    const int m = mrow + r;
                    if (m < NFD) slab[(size_t)m * KD + n] = acc[mf][nf][r];
                }
            }
        }
    }
}

// ---------------------------------------------------------------------------
// reduce (unchanged)
// ---------------------------------------------------------------------------
__global__ __launch_bounds__(256) void reduce_k(
    const float* __restrict__ partials, float* __restrict__ fhat, float* __restrict__ ghat)
{
    const int id = blockIdx.x * 256 + threadIdx.x;
    if (id >= NFD * KD) return;
    const int wb = blockIdx.y;
    const int wh = wb >> 4;
    const int b  = wb & 15;

    const float* p = partials + (size_t)(wh * NB + b) * SLABSZ + id;
    const size_t chstride = (size_t)2 * NB * SLABSZ;

    float s = 0.f;
    #pragma unroll
    for (int c = 0; c < NCH; ++c) s += p[c * chstride];

    float* dst = (wh ? ghat : fhat) + (size_t)b * NFD * KD + id;
    *dst = s;
}

// ---------------------------------------------------------------------------
// Generic TN SGEMM 64x64 tile — used by gram (unchanged, passing).
// ---------------------------------------------------------------------------
__device__ __forceinline__ void gemm_tn_64x64(
    const float* __restrict__ A, const float* __restrict__ B, float* __restrict__ C,
    int V, int M, int N, int m0, int n0)
{
    __shared__ float As[16][64];
    __shared__ float Bs[16][64];

    const int tid = threadIdx.x;
    const int tx = tid & 15;
    const int ty = tid >> 4;
    const int sr = tid >> 4;
    const int sc = (tid & 15) << 2;

    float acc[4][4] = {{0.f,0.f,0.f,0.f},{0.f,0.f,0.f,0.f},
                       {0.f,0.f,0.f,0.f},{0.f,0.f,0.f,0.f}};

    for (int v0 = 0; v0 < V; v0 += 16) {
        const int v = v0 + sr;
        float4 av; av.x = av.y = av.z = av.w = 0.f;
        float4 bv; bv.x = bv.y = bv.z = bv.w = 0.f;
        if (v < V) {
            const float* Ar = A + (size_t)v * M;
            const int ca = m0 + sc;
            if (ca + 3 < M) {
                av = *(const float4*)(Ar + ca);
            } else {
                if (ca + 0 < M) av.x = Ar[ca + 0];
                if (ca + 1 < M) av.y = Ar[ca + 1];
                if (ca + 2 < M) av.z = Ar[ca + 2];
                if (ca + 3 < M) av.w = Ar[ca + 3];
            }
            const float* Br = B + (size_t)v * N;
            const int cb = n0 + sc;
            if (cb + 3 < N) {
                bv = *(const float4*)(Br + cb);
            } else {
                if (cb + 0 < N) bv.x = Br[cb + 0];
                if (cb + 1 < N) bv.y = Br[cb + 1];
                if (cb + 2 < N) bv.z = Br[cb + 2];
                if (cb + 3 < N) bv.w = Br[cb + 3];
            }
        }
        __syncthreads();
        *(float4*)&As[sr][sc] = av;
        *(float4*)&Bs[sr][sc] = bv;
        __syncthreads();

        #pragma unroll
        for (int kk = 0; kk < 16; ++kk) {
            const float4 a4 = *(const float4*)&As[kk][ty << 2];
            const float4 b4 = *(const float4*)&Bs[kk][tx << 2];
            const float a[4]  = {a4.x, a4.y, a4.z, a4.w};
            const float bb[4] = {b4.x, b4.y, b4.z, b4.w};
            #pragma unroll
            for (int i = 0; i < 4; ++i)
                #pragma unroll
                for (int j = 0; j < 4; ++j)
                    acc[i][j] = fmaf(a[i], bb[j], acc[i][j]);
        }
    }

    #pragma unroll
    for (int i = 0; i < 4; ++i) {
        const int m = m0 + (ty << 2) + i;
        if (m < M) {
            #pragma unroll
            for (int j = 0; j < 4; ++j) {
                const int n = n0 + (tx << 2) + j;
                if (n < N) C[(size_t)m * N + n] = acc[i][j];
            }
        }
    }
}

__global__ __launch_bounds__(256) void gram_kernel(
    const float* __restrict__ fhat, const float* __restrict__ ghat,
    float* __restrict__ ftf, float* __restrict__ gtg, float* __restrict__ ftg)
{
    const int b = blockIdx.z;
    const int which = blockIdx.y;
    const int m0 = (blockIdx.x & 1) * 64;
    const int n0 = (blockIdx.x >> 1) * 64;

    const float* F = fhat + (size_t)b * NFD * KD;
    const float* G = ghat + (size_t)b * NFD * KD;
    const float* A  = (which == 1) ? G : F;
    const float* Bp = (which == 0) ? F : G;
    float* C = ((which == 0) ? ftf : (which == 1) ? gtg : ftg) + (size_t)b * KD * KD;

    gemm_tn_64x64(A, Bp, C, NFD, KD, KD, m0, n0);
}

// ---------------------------------------------------------------------------
// solve v6 (unchanged, passing): 480-thread Gauss-Jordan, 60 named scalars,
// padded 20-float prow segments (bank-clean), R=4 row reuse.
// ---------------------------------------------------------------------------
__device__ __forceinline__ float ldval(const float* __restrict__ A, const float* __restrict__ B,
                                       int pair, int row, int col) {
    if (col < KD) return A[row * KD + col];
    const int l = col - KD;
    return pair ? B[l * KD + row] : B[row * KD + l];
}

#define FOR15(OP) OP(0) OP(1) OP(2) OP(3) OP(4) OP(5) OP(6) OP(7) OP(8) OP(9) \
                  OP(10) OP(11) OP(12) OP(13) OP(14)

__global__ __launch_bounds__(480, 1) void solve_kernel(
    const float* __restrict__ ftf, const float* __restrict__ gtg,
    const float* __restrict__ ftg, float* __restrict__ out)
{
    const int pair = blockIdx.x;
    const int b = blockIdx.y;
    const int tid = threadIdx.x;
    const int cg = tid & 15;
    const int rg = tid >> 4;
    const int cbase = cg * 15;
    const int r0 = rg * 4;
    const int seg = cg * 20;

    const float* Ag = ((pair == 0) ? ftf : gtg) + (size_t)b * KD * KD;
    const float* Bg = ftg + (size_t)b * KD * KD;

    __shared__ __align__(16) float prow[2][320];
    __shared__ __align__(16) float pcol[2][120];

    #define DECL(I) float w##I = ldval(Ag, Bg, pair, r0 + 0, cbase + (I)); \
                    float x##I = ldval(Ag, Bg, pair, r0 + 1, cbase + (I)); \
                    float y##I = ldval(Ag, Bg, pair, r0 + 2, cbase + (I)); \
                    float z##I = ldval(Ag, Bg, pair, r0 + 3, cbase + (I));
    FOR15(DECL)
    #undef DECL

    if (rg == 0) {
        #define PUB0(I) prow[0][seg + (I)] = w##I;
        FOR15(PUB0)
        #undef PUB0
    }
    if (cg == 0) *(float4*)&pcol[0][r0] = float4{w0, x0, y0, z0};
    __syncthreads();

    int jseg = 0, joff = 0;

    for (int j = 0; j < KD; ++j) {
        const int cur = j & 1;
        const int nxt = cur ^ 1;

        const float pinv = 1.0f / prow[cur][jseg * 20 + joff];
        const float4 f4 = *(const float4*)&pcol[cur][r0];

        const float4 q0 = *(const float4*)&prow[cur][seg + 0];
        const float4 q1 = *(const float4*)&prow[cur][seg + 4];
        const float4 q2 = *(const float4*)&prow[cur][seg + 8];
        const float4 q3 = *(const float4*)&prow[cur][seg + 12];
        const float p0 = q0.x, p1 = q0.y, p2 = q0.z, p3 = q0.w;
        const float p4 = q1.x, p5 = q1.y, p6 = q1.z, p7 = q1.w;
        const float p8 = q2.x, p9 = q2.y, p10 = q2.z, p11 = q2.w;
        const float p12 = q3.x, p13 = q3.y, p14 = q3.z;

        const float fw = f4.x * pinv, fx = f4.y * pinv;
        const float fy = f4.z * pinv, fz = f4.w * pinv;

        #define UPD(I) w##I = fmaf(-fw, p##I, w##I); x##I = fmaf(-fx, p##I, x##I); \
                       y##I = fmaf(-fy, p##I, y##I); z##I = fmaf(-fz, p##I, z##I);
        FOR15(UPD)
        #undef UPD

        if (rg == (j >> 2)) {
            #define FW(I) w##I = p##I * pinv;
            #define FX(I) x##I = p##I * pinv;
            #define FY(I) y##I = p##I * pinv;
            #define FZ(I) z##I = p##I * pinv;
            switch (j & 3) {
                case 0: FOR15(FW) break;
                case 1: FOR15(FX) break;
                case 2: FOR15(FY) break;
                default: FOR15(FZ) break;
            }
            #undef FW
            #undef FX
            #undef FY
            #undef FZ
        }

        const int j2 = j + 1;

        if (j2 < KD && rg == (j2 >> 2)) {
            #define PW(I) prow[nxt][seg + (I)] = w##I;
            #define PX(I) prow[nxt][seg + (I)] = x##I;
            #define PY(I) prow[nxt][seg + (I)] = y##I;
            #define PZ(I) prow[nxt][seg + (I)] = z##I;
            switch (j2 & 3) {
                case 0: FOR15(PW) break;
                case 1: FOR15(PX) break;
                case 2: FOR15(PY) break;
                default: FOR15(PZ) break;
            }
            #undef PW
            #undef PX
            #undef PY
            #undef PZ
        }

        joff++; if (joff == 15) { joff = 0; jseg++; }
        if (j2 < KD && cg == jseg) {
            #define PC(I) case I: *(float4*)&pcol[nxt][r0] = float4{w##I, x##I, y##I, z##I}; break;
            switch (joff) {
                FOR15(PC)
                default: break;
            }
            #undef PC
        }
        __syncthreads();
    }

    if (cg >= 8) {
        float* op = out + (size_t)pair * NB * KD * KD + (size_t)b * KD * KD;
        #define OUTW(I) { const int l = cbase + (I) - KD; \
                          *(float4*)&op[l * KD + r0] = float4{w##I, x##I, y##I, z##I}; }
        FOR15(OUTW)
        #undef OUTW
    }
}

// ---------------------------------------------------------------------------
extern "C" void kernel_launch(void* const* d_in, const int* in_sizes, int n_in,
                              void* d_out, int out_size, void* d_ws, size_t ws_size,
                              hipStream_t stream)
{
    const float* feat_x  = (const float*)d_in[0];
    const float* feat_y  = (const float*)d_in[1];
    const float* evecs_x = (const float*)d_in[2];
    const float* evecs_y = (const float*)d_in[3];
    float* out = (float*)d_out;

    float* ws       = (float*)d_ws;
    float* partials = ws;
    float* fhat     = partials + (size_t)NCH * 2 * NB * SLABSZ;
    float* ghat     = fhat + (size_t)NB * NFD * KD;
    float* ftf      = ws;                                 // aliases partials (dead after reduce)
    float* gtg      = ftf + (size_t)NB * KD * KD;
    float* ftg      = gtg + (size_t)NB * KD * KD;

    proj_mfma <<<dim3(15, 2, NB), 256, 0, stream>>>(feat_x, feat_y, evecs_x, evecs_y, partials);
    reduce_k  <<<dim3(165, 32), 256, 0, stream>>>(partials, fhat, ghat);
    gram_kernel<<<dim3(4, 3, NB), 256, 0, stream>>>(fhat, ghat, ftf, gtg, ftg);
    solve_kernel<<<dim3(2, NB), 480, 0, stream>>>(ftf, gtg, ftg, out);
}